// Round 9
// baseline (8066.203 us; speedup 1.0000x reference)
//
#include <hip/hip_runtime.h>

// OptNet KKT layer: out = normalize(M^{-1} K^T), M = c1*Phi + c2*I (SPD, n=4096, 512 RHS).
// Blocked fp32 Cholesky with lookahead (potrf(k+1) = logical block 0 of syrk(k) dispatch).
// R9: all-row-major GEMM microkernel (conflict-free staging, strided-B reads),
// K=64 chunks -> 69.6KB LDS -> 2 blocks/CU -> 1 syrk round; potrf U-assembly via
// LDS column buffer (no global-U inner reads); register-accumulated diag update.

#define N    4096
#define NRHS 512
#define NB   128
#define PSTR 68    // row-major chunk stride [128][68]
#define DSTR 136   // potrf diag tile stride [128][136] (= Pa+Pb region)
#define TSTR 136   // solve staging stride (legacy, solves unchanged)
#define BSTR 68    // 64-wide RHS tile stride (solves)

__device__ __forceinline__ int xcd_map(int bid, int nwg) {
  int x = bid & 7, i = bid >> 3;
  int q = nwg >> 3, r = nwg & 7;
  return (x < r ? x * (q + 1) : r * (q + 1) + (x - r) * q) + i;
}

// ---------------- scalars ----------------
__global__ __launch_bounds__(256) void k_scalars(const float* __restrict__ imp,
                                                 const float* __restrict__ exc,
                                                 const float* __restrict__ gamma,
                                                 float* __restrict__ c) {
  __shared__ float red[256];
  int tid = threadIdx.x;
  float s = 0.0f;
  for (int i = tid; i < 1024; i += 256) { float x = imp[i], y = exc[i]; s += x * x + y * y; }
  red[tid] = s; __syncthreads();
  for (int w = 128; w > 0; w >>= 1) { if (tid < w) red[tid] += red[tid + w]; __syncthreads(); }
  if (tid == 0) { c[0] = red[0] / 512.0f; c[1] = gamma[0] / 512.0f; }
}

// ---------------- M = c1*Phi + c2*I ----------------
__global__ __launch_bounds__(256) void k_build_M(const float* __restrict__ Phi,
                                                 const float* __restrict__ c,
                                                 float* __restrict__ M) {
  int idx = blockIdx.x * 256 + threadIdx.x;
  int base = idx * 4;
  float4 p = *(const float4*)(Phi + base);
  float c1 = c[0], c2 = c[1];
  float4 m;
  m.x = c1 * p.x; m.y = c1 * p.y; m.z = c1 * p.z; m.w = c1 * p.w;
  int r = base >> 12, c0 = base & (N - 1);
  if (r == c0)     m.x += c2;
  if (r == c0 + 1) m.y += c2;
  if (r == c0 + 2) m.z += c2;
  if (r == c0 + 3) m.w += c2;
  *(float4*)(M + base) = m;
}

// ---------------- S[i][b] = K[b][i] ----------------
__global__ __launch_bounds__(256) void k_transpose(const float* __restrict__ K,
                                                   float* __restrict__ S) {
  __shared__ float t[32][33];
  int bi = blockIdx.x, bb = blockIdx.y;
  int tx = threadIdx.x & 31, ty = threadIdx.x >> 5;
  for (int r = 0; r < 4; ++r)
    t[ty + 8 * r][tx] = K[(size_t)(bb * 32 + ty + 8 * r) * N + bi * 32 + tx];
  __syncthreads();
  for (int r = 0; r < 4; ++r)
    S[(size_t)(bi * 32 + ty + 8 * r) * NRHS + bb * 32 + tx] = t[tx][ty + 8 * r];
}

// ---------------- fused syrk(panel k0) + lookahead potrf(kdiag) ----------------
__global__ __launch_bounds__(256, 2) void k_syrk_potrf(float* __restrict__ M,
                                                       float* __restrict__ U,
                                                       int kdiag, int k0) {
  __shared__ float sh[NB * DSTR];       // 69,632 B: syrk Pa|Pb ; potrf diag tile
  __shared__ float Ucol[NB][17];        //  8,704 B
  __shared__ float Wl[16][17];
  __shared__ float dinv[NB];
  float* Pa = sh;
  float* Pb = sh + NB * PSTR;
  int tid = threadIdx.x;
  int p = (gridDim.x > 1) ? xcd_map(blockIdx.x, gridDim.x) : 0;
  int g4 = tid >> 4;          // 16-lane group id
  int rr = g4 * 8;
  int cm = tid & 15;

  if (p > 0) {
    // ============ syrk role: C(br,bc) -= P_br P_bc^T ============
    int br = (int)((sqrtf(8.f * (float)p + 1.f) - 1.f) * 0.5f);
    while (((br + 1) * (br + 2)) / 2 <= p) ++br;
    while ((br * (br + 1)) / 2 > p) --br;
    int bc = p - (br * (br + 1)) / 2;
    int t0k = kdiag * NB;
    int r0 = t0k + br * NB, c0 = t0k + bc * NB;
    float acc[8][8] = {};
    for (int ch = 0; ch < 2; ++ch) {
      int kc = k0 + ch * 64;
      __syncthreads();
#pragma unroll
      for (int i = 0; i < 8; ++i) {
        int idx = tid + (i << 8);
        int r = idx >> 4, f4 = idx & 15;
        *(float4*)&Pa[r * PSTR + 4 * f4] = *(const float4*)(M + (size_t)(r0 + r) * N + kc + 4 * f4);
        *(float4*)&Pb[r * PSTR + 4 * f4] = *(const float4*)(M + (size_t)(c0 + r) * N + kc + 4 * f4);
      }
      __syncthreads();
#pragma unroll 2
      for (int tc = 0; tc < 64; tc += 4) {
        float4 a4[8], b4[8];
#pragma unroll
        for (int q = 0; q < 8; ++q) a4[q] = *(const float4*)&Pa[(rr + ((q + g4) & 7)) * PSTR + tc];
#pragma unroll
        for (int w = 0; w < 8; ++w) b4[w] = *(const float4*)&Pb[(cm + 16 * w) * PSTR + tc];
#pragma unroll
        for (int q = 0; q < 8; ++q)
#pragma unroll
          for (int w = 0; w < 8; ++w)
            acc[q][w] += a4[q].x * b4[w].x + a4[q].y * b4[w].y
                       + a4[q].z * b4[w].z + a4[q].w * b4[w].w;
      }
    }
    for (int q = 0; q < 8; ++q) {
      int row = r0 + rr + ((q + g4) & 7);
      float* mp = M + (size_t)row * N + c0 + cm;
#pragma unroll
      for (int w = 0; w < 8; ++w) mp[16 * w] -= acc[q][w];
    }
    return;
  }

  // ============ potrf role ============
  int kr = kdiag * NB;
  float acc[8][8] = {};
  if (k0 >= 0) {   // D -= P P^T accumulated in registers over 2 chunks
    for (int ch = 0; ch < 2; ++ch) {
      int kc = k0 + ch * 64;
      __syncthreads();
#pragma unroll
      for (int i = 0; i < 8; ++i) {
        int idx = tid + (i << 8);
        int r = idx >> 4, f4 = idx & 15;
        *(float4*)&Pa[r * PSTR + 4 * f4] = *(const float4*)(M + (size_t)(kr + r) * N + kc + 4 * f4);
      }
      __syncthreads();
#pragma unroll 2
      for (int tc = 0; tc < 64; tc += 4) {
        float4 a4[8], b4[8];
#pragma unroll
        for (int q = 0; q < 8; ++q) a4[q] = *(const float4*)&Pa[(rr + ((q + g4) & 7)) * PSTR + tc];
#pragma unroll
        for (int w = 0; w < 8; ++w) b4[w] = *(const float4*)&Pa[(cm + 16 * w) * PSTR + tc];
#pragma unroll
        for (int q = 0; q < 8; ++q)
#pragma unroll
          for (int w = 0; w < 8; ++w)
            acc[q][w] += a4[q].x * b4[w].x + a4[q].y * b4[w].y
                       + a4[q].z * b4[w].z + a4[q].w * b4[w].w;
      }
    }
  }
  __syncthreads();
  // stage diag tile into sh (stride DSTR), overwrite Pa/Pb region
#pragma unroll
  for (int i = 0; i < 16; ++i) {
    int idx = tid + (i << 8);
    int r = idx >> 5, f4 = idx & 31;
    *(float4*)&sh[r * DSTR + 4 * f4] = *(const float4*)(M + (size_t)(kr + r) * N + kr + 4 * f4);
  }
  __syncthreads();
  if (k0 >= 0) {
#pragma unroll
    for (int q = 0; q < 8; ++q) {
      int row = rr + ((q + g4) & 7);
#pragma unroll
      for (int w = 0; w < 8; ++w)
        sh[row * DSTR + cm + 16 * w] -= acc[q][w];
    }
  }
  __syncthreads();

  // ---- factor: 8 panels of 16 columns; V^T stored in upper of diag block ----
#pragma unroll 1
  for (int pp = 0; pp < 8; ++pp) {
    const int b0 = 16 * pp;
    if (tid < 16) {
      int l = tid;
      float r[16];
#pragma unroll
      for (int t = 0; t < 16; ++t) r[t] = sh[(b0 + l) * DSTR + b0 + t];
#pragma unroll
      for (int j = 0; j < 16; ++j) {
        float d = __shfl(r[j], j);
        float inv = rsqrtf(d);
        if (l == j) r[j] = d * inv;
        else if (l > j) r[j] *= inv;
        if (l == 0) dinv[b0 + j] = inv;
#pragma unroll
        for (int t = j + 1; t < 16; ++t) {
          float Ltj = __shfl(r[j], t);
          if (l >= t) r[t] -= r[j] * Ltj;
        }
      }
#pragma unroll
      for (int t = 0; t < 16; ++t) if (t <= l) sh[(b0 + l) * DSTR + b0 + t] = r[t];
      float x[16];
#pragma unroll
      for (int i = 0; i < 16; ++i) {
        float s = (l == i) ? 1.0f : 0.0f;
#pragma unroll
        for (int t = 0; t < 16; ++t)
          if (t < i) s -= __shfl(r[t], i) * x[t];
        x[i] = s * dinv[b0 + i];
      }
#pragma unroll
      for (int i = 0; i < 16; ++i)
        if (i > l) sh[(b0 + l) * DSTR + b0 + i] = x[i];  // V^T strict upper
    }
    __syncthreads();
    const int base = b0 + 16, nbl = NB - base;
    if (nbl > 0) {
      // strip TRSM: L[r][b0+c] = sum_{t<=c} A[r][b0+t] * V[c][t]
      const int cnt = nbl * 16;
      float pv[7];
#pragma unroll
      for (int e = 0; e < 7; ++e) {
        int idx = tid + e * 256;
        if (idx < cnt) {
          int r2 = base + (idx >> 4), c2 = idx & 15;
          float s = 0.0f;
          for (int t = 0; t < c2; ++t)
            s += sh[r2 * DSTR + b0 + t] * sh[(b0 + t) * DSTR + b0 + c2];  // V^T[t][c2]
          s += sh[r2 * DSTR + b0 + c2] * dinv[b0 + c2];
          pv[e] = s;
        }
      }
      __syncthreads();
#pragma unroll
      for (int e = 0; e < 7; ++e) {
        int idx = tid + e * 256;
        if (idx < cnt) {
          int r2 = base + (idx >> 4), c2 = idx & 15;
          sh[r2 * DSTR + b0 + c2] = pv[e];
        }
      }
      __syncthreads();
      // rank-16 trailing update (lower incl diag), div-free mapping
      for (int i = tid >> 3; i < nbl; i += 32) {
        const float* ai = &sh[(base + i) * DSTR + b0];
        float4 a0 = *(const float4*)ai,       a1 = *(const float4*)(ai + 4);
        float4 a2 = *(const float4*)(ai + 8), a3 = *(const float4*)(ai + 12);
        for (int j = tid & 7; j <= i; j += 8) {
          const float* bj = &sh[(base + j) * DSTR + b0];
          float4 c0 = *(const float4*)bj,       c1 = *(const float4*)(bj + 4);
          float4 c2 = *(const float4*)(bj + 8), c3 = *(const float4*)(bj + 12);
          float s = a0.x*c0.x + a0.y*c0.y + a0.z*c0.z + a0.w*c0.w
                  + a1.x*c1.x + a1.y*c1.y + a1.z*c1.z + a1.w*c1.w
                  + a2.x*c2.x + a2.y*c2.y + a2.z*c2.z + a2.w*c2.w
                  + a3.x*c3.x + a3.y*c3.y + a3.z*c3.z + a3.w*c3.w;
          sh[(base + i) * DSTR + base + j] -= s;
        }
      }
      __syncthreads();
    }
  }

  // ---- U = L^{-1} assembly, per 16-column block, forward substitution via Ucol ----
  {
    int r2 = tid >> 4, c2 = tid & 15;
#pragma unroll 1
    for (int j = 0; j < 8; ++j) {
      {  // diag block V_j -> U and Ucol ; zero blocks above
        float v;
        if (c2 > r2) v = 0.0f;
        else if (c2 == r2) v = dinv[16 * j + r2];
        else v = sh[(16 * j + c2) * DSTR + 16 * j + r2];
        U[(size_t)(16 * j + r2) * NB + 16 * j + c2] = v;
        Ucol[16 * j + r2][c2] = v;
      }
      for (int e = tid; e < 16 * j * 16; e += 256) {
        int zr = e >> 4, zc = e & 15;
        U[(size_t)zr * NB + 16 * j + zc] = 0.0f;
      }
      __syncthreads();
#pragma unroll 1
      for (int i = j + 1; i < 8; ++i) {
        float s = 0.0f;
        for (int t = 16 * j; t < 16 * i; ++t)
          s += sh[(16 * i + r2) * DSTR + t] * Ucol[t][c2];
        Wl[r2][c2] = s;
        __syncthreads();
        float s2 = 0.0f;
        for (int u = 0; u < r2; ++u)
          s2 += sh[(16 * i + u) * DSTR + 16 * i + r2] * Wl[u][c2];  // V_i[r2][u] = V^T[u][r2]
        s2 += dinv[16 * i + r2] * Wl[r2][c2];
        s2 = -s2;
        U[(size_t)(16 * i + r2) * NB + 16 * j + c2] = s2;
        Ucol[16 * i + r2][c2] = s2;
        __syncthreads();
      }
    }
  }
}

// ---------------- panel TRSM as GEMM: P := P_old * U^T ----------------
__global__ __launch_bounds__(256, 2) void k_trsm(float* __restrict__ M,
                                                 const float* __restrict__ Ug, int k0) {
  __shared__ float Pa[NB * PSTR];
  __shared__ float Pb[NB * PSTR];
  int tid = threadIdx.x;
  int g4 = tid >> 4, rr = g4 * 8, cm = tid & 15;
  int r0 = k0 + NB + blockIdx.x * NB;
  float acc[8][8] = {};
  for (int ch = 0; ch < 2; ++ch) {
    int kc = k0 + ch * 64;
    __syncthreads();
#pragma unroll
    for (int i = 0; i < 8; ++i) {
      int idx = tid + (i << 8);
      int r = idx >> 4, f4 = idx & 15;
      *(float4*)&Pa[r * PSTR + 4 * f4] = *(const float4*)(M + (size_t)(r0 + r) * N + kc + 4 * f4);
      *(float4*)&Pb[r * PSTR + 4 * f4] = *(const float4*)(Ug + (size_t)r * NB + ch * 64 + 4 * f4);
    }
    __syncthreads();
#pragma unroll 2
    for (int tc = 0; tc < 64; tc += 4) {
      float4 a4[8], b4[8];
#pragma unroll
      for (int q = 0; q < 8; ++q) a4[q] = *(const float4*)&Pa[(rr + ((q + g4) & 7)) * PSTR + tc];
#pragma unroll
      for (int w = 0; w < 8; ++w) b4[w] = *(const float4*)&Pb[(cm + 16 * w) * PSTR + tc];
#pragma unroll
      for (int q = 0; q < 8; ++q)
#pragma unroll
        for (int w = 0; w < 8; ++w)
          acc[q][w] += a4[q].x * b4[w].x + a4[q].y * b4[w].y
                     + a4[q].z * b4[w].z + a4[q].w * b4[w].w;
    }
  }
  for (int q = 0; q < 8; ++q) {
    int row = r0 + rr + ((q + g4) & 7);
    float* mp = M + (size_t)row * N + k0 + cm;
#pragma unroll
    for (int w = 0; w < 8; ++w) mp[16 * w] = acc[q][w];
  }
}

// ---------------- fused forward solve step k (unchanged from R8) ----------------
__global__ __launch_bounds__(256) void k_fsolve(float* __restrict__ S,
                                                float* __restrict__ X,
                                                const float* __restrict__ M,
                                                const float* __restrict__ Uk,
                                                int k0) {
  __shared__ float Xl[NB][BSTR];
  __shared__ float Aa[16][TSTR];
  __shared__ float Bb[16][BSTR];
  int tid = threadIdx.x;
  int id = xcd_map(blockIdx.x, gridDim.x);
  int d = id >> 3;
  int b0 = (id & 7) * 64;
  int i0g = k0 + d * NB;
  int ii = (tid >> 3) * 4, bl = (tid & 7) * 8;
  float acc[4][8] = {};
  for (int tch = 0; tch < NB; tch += 16) {
#pragma unroll
    for (int it = 0; it < 2; ++it) {
      int idx = tid + it * 256;
      int j = idx >> 2, f4 = idx & 3;
      const float4 v = *(const float4*)(Uk + (size_t)j * NB + tch + 4 * f4);
      Aa[4 * f4 + 0][j] = v.x; Aa[4 * f4 + 1][j] = v.y;
      Aa[4 * f4 + 2][j] = v.z; Aa[4 * f4 + 3][j] = v.w;
    }
    {
      int t = tid >> 4, f = tid & 15;
      *(float4*)&Bb[t][4 * f] = *(const float4*)(S + (size_t)(k0 + tch + t) * NRHS + b0 + 4 * f);
    }
    __syncthreads();
#pragma unroll 4
    for (int t = 0; t < 16; ++t) {
      float4 a0 = *(const float4*)&Aa[t][ii];
      float4 b0v = *(const float4*)&Bb[t][bl];
      float4 b1v = *(const float4*)&Bb[t][bl + 4];
      float av[4] = {a0.x, a0.y, a0.z, a0.w};
      float bv[8] = {b0v.x, b0v.y, b0v.z, b0v.w, b1v.x, b1v.y, b1v.z, b1v.w};
#pragma unroll
      for (int q = 0; q < 4; ++q)
#pragma unroll
        for (int w = 0; w < 8; ++w) acc[q][w] += av[q] * bv[w];
    }
    __syncthreads();
  }
  if (d == 0) {
    for (int q = 0; q < 4; ++q) {
      float* xp = X + (size_t)(k0 + ii + q) * NRHS + b0 + bl;
      float4 x0 = {acc[q][0], acc[q][1], acc[q][2], acc[q][3]};
      float4 x1 = {acc[q][4], acc[q][5], acc[q][6], acc[q][7]};
      *(float4*)xp = x0; *((float4*)xp + 1) = x1;
    }
    return;
  }
  for (int q = 0; q < 4; ++q) {
    float4 x0 = {acc[q][0], acc[q][1], acc[q][2], acc[q][3]};
    float4 x1 = {acc[q][4], acc[q][5], acc[q][6], acc[q][7]};
    *(float4*)&Xl[ii + q][bl] = x0; *(float4*)&Xl[ii + q][bl + 4] = x1;
  }
  __syncthreads();
  float acc2[4][8] = {};
  for (int tch = 0; tch < NB; tch += 16) {
    for (int idx = tid; idx < 512; idx += 256) {
      int r = idx >> 2, q = idx & 3;
      const float4 v = *(const float4*)(M + (size_t)(i0g + r) * N + k0 + tch + 4 * q);
      Aa[4 * q + 0][r] = v.x; Aa[4 * q + 1][r] = v.y;
      Aa[4 * q + 2][r] = v.z; Aa[4 * q + 3][r] = v.w;
    }
    __syncthreads();
#pragma unroll 4
    for (int t = 0; t < 16; ++t) {
      float4 a0 = *(const float4*)&Aa[t][ii];
      float4 b0v = *(const float4*)&Xl[tch + t][bl];
      float4 b1v = *(const float4*)&Xl[tch + t][bl + 4];
      float av[4] = {a0.x, a0.y, a0.z, a0.w};
      float bv[8] = {b0v.x, b0v.y, b0v.z, b0v.w, b1v.x, b1v.y, b1v.z, b1v.w};
#pragma unroll
      for (int q = 0; q < 4; ++q)
#pragma unroll
        for (int w = 0; w < 8; ++w) acc2[q][w] += av[q] * bv[w];
    }
    __syncthreads();
  }
  for (int q = 0; q < 4; ++q) {
    float* sp = S + (size_t)(i0g + ii + q) * NRHS + b0 + bl;
    float4 x0 = *(float4*)sp, x1 = *((float4*)sp + 1);
    x0.x -= acc2[q][0]; x0.y -= acc2[q][1]; x0.z -= acc2[q][2]; x0.w -= acc2[q][3];
    x1.x -= acc2[q][4]; x1.y -= acc2[q][5]; x1.z -= acc2[q][6]; x1.w -= acc2[q][7];
    *(float4*)sp = x0; *((float4*)sp + 1) = x1;
  }
}

// ---------------- fused backward solve step k (unchanged from R8) ----------------
__global__ __launch_bounds__(256) void k_bsolve(float* __restrict__ X,
                                                float* __restrict__ S,
                                                const float* __restrict__ M,
                                                const float* __restrict__ Uk,
                                                int k0) {
  __shared__ float Xl[NB][BSTR];
  __shared__ float Aa[16][TSTR];
  __shared__ float Bb[16][BSTR];
  int tid = threadIdx.x;
  int id = xcd_map(blockIdx.x, gridDim.x);
  int d = id >> 3;
  int b0 = (id & 7) * 64;
  int i0g = k0 - d * NB;
  int ii = (tid >> 3) * 4, bl = (tid & 7) * 8;
  float acc[4][8] = {};
  for (int tch = 0; tch < NB; tch += 16) {
    for (int idx = tid; idx < 512; idx += 256) {
      int t = idx >> 5, f = idx & 31;
      *(float4*)&Aa[t][4 * f] = *(const float4*)(Uk + (size_t)(tch + t) * NB + 4 * f);
    }
    {
      int t = tid >> 4, f = tid & 15;
      *(float4*)&Bb[t][4 * f] = *(const float4*)(X + (size_t)(k0 + tch + t) * NRHS + b0 + 4 * f);
    }
    __syncthreads();
#pragma unroll 4
    for (int t = 0; t < 16; ++t) {
      float4 a0 = *(const float4*)&Aa[t][ii];
      float4 b0v = *(const float4*)&Bb[t][bl];
      float4 b1v = *(const float4*)&Bb[t][bl + 4];
      float av[4] = {a0.x, a0.y, a0.z, a0.w};
      float bv[8] = {b0v.x, b0v.y, b0v.z, b0v.w, b1v.x, b1v.y, b1v.z, b1v.w};
#pragma unroll
      for (int q = 0; q < 4; ++q)
#pragma unroll
        for (int w = 0; w < 8; ++w) acc[q][w] += av[q] * bv[w];
    }
    __syncthreads();
  }
  if (d == 0) {
    for (int q = 0; q < 4; ++q) {
      float* sp = S + (size_t)(k0 + ii + q) * NRHS + b0 + bl;
      float4 x0 = {acc[q][0], acc[q][1], acc[q][2], acc[q][3]};
      float4 x1 = {acc[q][4], acc[q][5], acc[q][6], acc[q][7]};
      *(float4*)sp = x0; *((float4*)sp + 1) = x1;
    }
    return;
  }
  for (int q = 0; q < 4; ++q) {
    float4 x0 = {acc[q][0], acc[q][1], acc[q][2], acc[q][3]};
    float4 x1 = {acc[q][4], acc[q][5], acc[q][6], acc[q][7]};
    *(float4*)&Xl[ii + q][bl] = x0; *(float4*)&Xl[ii + q][bl + 4] = x1;
  }
  __syncthreads();
  float acc2[4][8] = {};
  for (int tch = 0; tch < NB; tch += 16) {
    for (int idx = tid; idx < 512; idx += 256) {
      int t = idx >> 5, f = idx & 31;
      *(float4*)&Aa[t][4 * f] = *(const float4*)(M + (size_t)(k0 + tch + t) * N + i0g + 4 * f);
    }
    __syncthreads();
#pragma unroll 4
    for (int t = 0; t < 16; ++t) {
      float4 a0 = *(const float4*)&Aa[t][ii];
      float4 b0v = *(const float4*)&Xl[tch + t][bl];
      float4 b1v = *(const float4*)&Xl[tch + t][bl + 4];
      float av[4] = {a0.x, a0.y, a0.z, a0.w};
      float bv[8] = {b0v.x, b0v.y, b0v.z, b0v.w, b1v.x, b1v.y, b1v.z, b1v.w};
#pragma unroll
      for (int q = 0; q < 4; ++q)
#pragma unroll
        for (int w = 0; w < 8; ++w) acc2[q][w] += av[q] * bv[w];
    }
    __syncthreads();
  }
  for (int q = 0; q < 4; ++q) {
    float* xp = X + (size_t)(i0g + ii + q) * NRHS + b0 + bl;
    float4 x0 = *(float4*)xp, x1 = *((float4*)xp + 1);
    x0.x -= acc2[q][0]; x0.y -= acc2[q][1]; x0.z -= acc2[q][2]; x0.w -= acc2[q][3];
    x1.x -= acc2[q][4]; x1.y -= acc2[q][5]; x1.z -= acc2[q][6]; x1.w -= acc2[q][7];
    *(float4*)xp = x0; *((float4*)xp + 1) = x1;
  }
}

// ---------------- denom + normalize + transpose to output ----------------
__global__ __launch_bounds__(256) void k_final(const float* __restrict__ S,
                                               const float* __restrict__ K,
                                               const float* __restrict__ a_ptr,
                                               float* __restrict__ out) {
  __shared__ float red[256];
  int b = blockIdx.x, tid = threadIdx.x;
  float s = 0.0f;
  for (int i = tid; i < N; i += 256) s += S[(size_t)i * NRHS + b] * K[(size_t)b * N + i];
  red[tid] = s; __syncthreads();
  for (int w = 128; w > 0; w >>= 1) { if (tid < w) red[tid] += red[tid + w]; __syncthreads(); }
  float inv = 1.0f / (a_ptr[0] * red[0]);
  for (int i = tid; i < N; i += 256) out[(size_t)b * N + i] = S[(size_t)i * NRHS + b] * inv;
}

extern "C" void kernel_launch(void* const* d_in, const int* in_sizes, int n_in,
                              void* d_out, int out_size, void* d_ws, size_t ws_size,
                              hipStream_t stream) {
  const float* Kb    = (const float*)d_in[0];
  const float* a     = (const float*)d_in[1];
  const float* exc   = (const float*)d_in[2];
  const float* imp   = (const float*)d_in[3];
  const float* Phi   = (const float*)d_in[4];
  const float* gamma = (const float*)d_in[5];
  float* out = (float*)d_out;

  float* M  = (float*)d_ws;                        // n*n            (64 MiB)
  float* S  = M + (size_t)N * N;                   // n*NRHS         (8 MiB)
  float* X  = S + (size_t)N * NRHS;                // n*NRHS         (8 MiB)
  float* U  = X + (size_t)N * NRHS;                // 32 * 128*128   (2 MiB)
  float* c  = U + (size_t)32 * NB * NB;            // scalars

  k_scalars<<<1, 256, 0, stream>>>(imp, exc, gamma, c);
  k_build_M<<<N * N / 1024, 256, 0, stream>>>(Phi, c, M);
  k_transpose<<<dim3(N / 32, NRHS / 32), 256, 0, stream>>>(Kb, S);

  // potrf(0) standalone
  k_syrk_potrf<<<1, 256, 0, stream>>>(M, U, 0, -1);
  for (int k = 0; k <= 30; ++k) {
    int k0 = k * NB;
    k_trsm<<<31 - k, 256, 0, stream>>>(M, U + (size_t)k * NB * NB, k0);
    int T = 31 - k;
    int pairs = (T * (T + 1)) / 2;   // logical block 0 = lookahead potrf(k+1)
    k_syrk_potrf<<<pairs, 256, 0, stream>>>(M, U + (size_t)(k + 1) * NB * NB, k + 1, k0);
  }
  for (int k = 0; k < 32; ++k)
    k_fsolve<<<8 * (32 - k), 256, 0, stream>>>(S, X, M, U + (size_t)k * NB * NB, k * NB);
  for (int k = 31; k >= 0; --k)
    k_bsolve<<<8 * (k + 1), 256, 0, stream>>>(X, S, M, U + (size_t)k * NB * NB, k * NB);
  k_final<<<NRHS, 256, 0, stream>>>(S, Kb, a, out);
}

// Round 10
// 6577.850 us; speedup vs baseline: 1.2263x; 1.2263x over previous
//
#include <hip/hip_runtime.h>

// OptNet KKT layer: out = normalize(M^{-1} K^T), M = c1*Phi + c2*I (SPD, n=4096, 512 RHS).
// Blocked fp32 Cholesky with lookahead (potrf(k+1) = logical block 0 of syrk(k) dispatch).
// R10: potrf's U=L^{-1} assembly rewritten as RECURSIVE DOUBLING (3 levels of parallel
// GEMMs, in-place over dead L blocks, W in dead upper-right LDS quadrant) replacing the
// 56-barrier serial assembly that gated every fused dispatch at ~180us.

#define N    4096
#define NRHS 512
#define NB   128
#define PSTR 68    // row-major chunk stride [128][68]
#define DSTR 136   // potrf diag tile stride (= Pa|Pb region)
#define TSTR 136   // solve staging stride
#define BSTR 68    // 64-wide RHS tile stride (solves)

__device__ __forceinline__ int xcd_map(int bid, int nwg) {
  int x = bid & 7, i = bid >> 3;
  int q = nwg >> 3, r = nwg & 7;
  return (x < r ? x * (q + 1) : r * (q + 1) + (x - r) * q) + i;
}

// ---- recursive-doubling assembly phases: W = A*U1 ; U_off = -U2*W ----
template<int S>
__device__ __forceinline__ void asm_levelA(float* __restrict__ sh, int tid) {
  constexpr int PER = S / 16;      // float4 outputs per thread
  constexpr int F4 = S / 4;
#pragma unroll
  for (int e = 0; e < PER; ++e) {
    int id = tid + (e << 8);
    int pair = id / (S * F4);
    int rem = id - pair * (S * F4);
    int r = rem / F4, c4 = rem - r * F4;
    int o = 2 * S * pair;
    const float* arow = &sh[(o + S + r) * DSTR + o];
    float4 a4 = {0.f, 0.f, 0.f, 0.f};
    for (int t = 0; t < S; ++t) {
      float a = arow[t];
      const float4 b = *(const float4*)&sh[(o + t) * DSTR + o + 4 * c4];
      a4.x += a * b.x; a4.y += a * b.y; a4.z += a * b.z; a4.w += a * b.w;
    }
    *(float4*)&sh[(S * pair + r) * DSTR + 64 + 4 * c4] = a4;   // W region
  }
}
template<int S>
__device__ __forceinline__ void asm_levelB(float* __restrict__ sh, int tid) {
  constexpr int PER = S / 16;
  constexpr int F4 = S / 4;
#pragma unroll
  for (int e = 0; e < PER; ++e) {
    int id = tid + (e << 8);
    int pair = id / (S * F4);
    int rem = id - pair * (S * F4);
    int r = rem / F4, c4 = rem - r * F4;
    int o = 2 * S * pair;
    const float* u2row = &sh[(o + S + r) * DSTR + o + S];
    float4 a4 = {0.f, 0.f, 0.f, 0.f};
    for (int t = 0; t < S; ++t) {
      float a = u2row[t];
      const float4 w = *(const float4*)&sh[(S * pair + t) * DSTR + 64 + 4 * c4];
      a4.x += a * w.x; a4.y += a * w.y; a4.z += a * w.z; a4.w += a * w.w;
    }
    float4 ov = {-a4.x, -a4.y, -a4.z, -a4.w};
    *(float4*)&sh[(o + S + r) * DSTR + o + 4 * c4] = ov;       // over dead A block
  }
}

// ---------------- scalars ----------------
__global__ __launch_bounds__(256) void k_scalars(const float* __restrict__ imp,
                                                 const float* __restrict__ exc,
                                                 const float* __restrict__ gamma,
                                                 float* __restrict__ c) {
  __shared__ float red[256];
  int tid = threadIdx.x;
  float s = 0.0f;
  for (int i = tid; i < 1024; i += 256) { float x = imp[i], y = exc[i]; s += x * x + y * y; }
  red[tid] = s; __syncthreads();
  for (int w = 128; w > 0; w >>= 1) { if (tid < w) red[tid] += red[tid + w]; __syncthreads(); }
  if (tid == 0) { c[0] = red[0] / 512.0f; c[1] = gamma[0] / 512.0f; }
}

// ---------------- M = c1*Phi + c2*I ----------------
__global__ __launch_bounds__(256) void k_build_M(const float* __restrict__ Phi,
                                                 const float* __restrict__ c,
                                                 float* __restrict__ M) {
  int idx = blockIdx.x * 256 + threadIdx.x;
  int base = idx * 4;
  float4 p = *(const float4*)(Phi + base);
  float c1 = c[0], c2 = c[1];
  float4 m;
  m.x = c1 * p.x; m.y = c1 * p.y; m.z = c1 * p.z; m.w = c1 * p.w;
  int r = base >> 12, c0 = base & (N - 1);
  if (r == c0)     m.x += c2;
  if (r == c0 + 1) m.y += c2;
  if (r == c0 + 2) m.z += c2;
  if (r == c0 + 3) m.w += c2;
  *(float4*)(M + base) = m;
}

// ---------------- S[i][b] = K[b][i] ----------------
__global__ __launch_bounds__(256) void k_transpose(const float* __restrict__ K,
                                                   float* __restrict__ S) {
  __shared__ float t[32][33];
  int bi = blockIdx.x, bb = blockIdx.y;
  int tx = threadIdx.x & 31, ty = threadIdx.x >> 5;
  for (int r = 0; r < 4; ++r)
    t[ty + 8 * r][tx] = K[(size_t)(bb * 32 + ty + 8 * r) * N + bi * 32 + tx];
  __syncthreads();
  for (int r = 0; r < 4; ++r)
    S[(size_t)(bi * 32 + ty + 8 * r) * NRHS + bb * 32 + tx] = t[tx][ty + 8 * r];
}

// ---------------- fused syrk(panel k0) + lookahead potrf(kdiag) ----------------
__global__ __launch_bounds__(256, 2) void k_syrk_potrf(float* __restrict__ M,
                                                       float* __restrict__ U,
                                                       int kdiag, int k0) {
  __shared__ float sh[NB * DSTR];      // 69,632 B
  __shared__ float dinv[NB];
  float* Pa = sh;
  float* Pb = sh + NB * PSTR;
  int tid = threadIdx.x;
  int p = (gridDim.x > 1) ? xcd_map(blockIdx.x, gridDim.x) : 0;
  int g4 = tid >> 4;
  int rr = g4 * 8;
  int cm = tid & 15;

  if (p > 0) {
    // ============ syrk role: C(br,bc) -= P_br P_bc^T ============
    int br = (int)((sqrtf(8.f * (float)p + 1.f) - 1.f) * 0.5f);
    while (((br + 1) * (br + 2)) / 2 <= p) ++br;
    while ((br * (br + 1)) / 2 > p) --br;
    int bc = p - (br * (br + 1)) / 2;
    int t0k = kdiag * NB;
    int r0 = t0k + br * NB, c0 = t0k + bc * NB;
    float acc[8][8] = {};
    for (int ch = 0; ch < 2; ++ch) {
      int kc = k0 + ch * 64;
      __syncthreads();
#pragma unroll
      for (int i = 0; i < 8; ++i) {
        int idx = tid + (i << 8);
        int r = idx >> 4, f4 = idx & 15;
        *(float4*)&Pa[r * PSTR + 4 * f4] = *(const float4*)(M + (size_t)(r0 + r) * N + kc + 4 * f4);
        *(float4*)&Pb[r * PSTR + 4 * f4] = *(const float4*)(M + (size_t)(c0 + r) * N + kc + 4 * f4);
      }
      __syncthreads();
#pragma unroll 2
      for (int tc = 0; tc < 64; tc += 4) {
        float4 a4[8], b4[8];
#pragma unroll
        for (int q = 0; q < 8; ++q) a4[q] = *(const float4*)&Pa[(rr + ((q + g4) & 7)) * PSTR + tc];
#pragma unroll
        for (int w = 0; w < 8; ++w) b4[w] = *(const float4*)&Pb[(cm + 16 * w) * PSTR + tc];
#pragma unroll
        for (int q = 0; q < 8; ++q)
#pragma unroll
          for (int w = 0; w < 8; ++w)
            acc[q][w] += a4[q].x * b4[w].x + a4[q].y * b4[w].y
                       + a4[q].z * b4[w].z + a4[q].w * b4[w].w;
      }
    }
    for (int q = 0; q < 8; ++q) {
      int row = r0 + rr + ((q + g4) & 7);
      float* mp = M + (size_t)row * N + c0 + cm;
#pragma unroll
      for (int w = 0; w < 8; ++w) mp[16 * w] -= acc[q][w];
    }
    return;
  }

  // ============ potrf role ============
  int kr = kdiag * NB;
  float acc[8][8] = {};
  if (k0 >= 0) {   // D -= P P^T accumulated in registers over 2 chunks
    for (int ch = 0; ch < 2; ++ch) {
      int kc = k0 + ch * 64;
      __syncthreads();
#pragma unroll
      for (int i = 0; i < 8; ++i) {
        int idx = tid + (i << 8);
        int r = idx >> 4, f4 = idx & 15;
        *(float4*)&Pa[r * PSTR + 4 * f4] = *(const float4*)(M + (size_t)(kr + r) * N + kc + 4 * f4);
      }
      __syncthreads();
#pragma unroll 2
      for (int tc = 0; tc < 64; tc += 4) {
        float4 a4[8], b4[8];
#pragma unroll
        for (int q = 0; q < 8; ++q) a4[q] = *(const float4*)&Pa[(rr + ((q + g4) & 7)) * PSTR + tc];
#pragma unroll
        for (int w = 0; w < 8; ++w) b4[w] = *(const float4*)&Pa[(cm + 16 * w) * PSTR + tc];
#pragma unroll
        for (int q = 0; q < 8; ++q)
#pragma unroll
          for (int w = 0; w < 8; ++w)
            acc[q][w] += a4[q].x * b4[w].x + a4[q].y * b4[w].y
                       + a4[q].z * b4[w].z + a4[q].w * b4[w].w;
      }
    }
  }
  __syncthreads();
  // stage diag tile row-major (stride DSTR)
#pragma unroll
  for (int i = 0; i < 16; ++i) {
    int idx = tid + (i << 8);
    int r = idx >> 5, f4 = idx & 31;
    *(float4*)&sh[r * DSTR + 4 * f4] = *(const float4*)(M + (size_t)(kr + r) * N + kr + 4 * f4);
  }
  __syncthreads();
  // apply acc to lower blocks; zero strictly-upper 16-blocks (one phase)
#pragma unroll
  for (int q = 0; q < 8; ++q) {
    int row = rr + ((q + g4) & 7);
#pragma unroll
    for (int w = 0; w < 8; ++w) {
      int col = cm + 16 * w;
      if ((row >> 4) < (col >> 4)) sh[row * DSTR + col] = 0.0f;
      else if (k0 >= 0) sh[row * DSTR + col] -= acc[q][w];
    }
  }
  __syncthreads();

  // ---- factor: 8 panels of 16 columns; V^T in corner upper; corners -> V in place ----
#pragma unroll 1
  for (int pp = 0; pp < 8; ++pp) {
    const int b0 = 16 * pp;
    if (tid < 16) {
      int l = tid;
      if (pp > 0) {   // convert corner pp-1 (V^T upper + dinv) -> V proper
        const int a0 = 16 * (pp - 1);
        float colv[16];
#pragma unroll
        for (int i = 0; i < 16; ++i) colv[i] = sh[(a0 + l) * DSTR + a0 + i];
#pragma unroll
        for (int i = 0; i < 16; ++i) {
          float v = (i > l) ? colv[i] : ((i == l) ? dinv[a0 + l] : 0.0f);
          sh[(a0 + i) * DSTR + a0 + l] = v;
        }
      }
      // 16x16 corner factor in registers (shfl)
      float r[16];
#pragma unroll
      for (int t = 0; t < 16; ++t) r[t] = sh[(b0 + l) * DSTR + b0 + t];
#pragma unroll
      for (int j = 0; j < 16; ++j) {
        float d = __shfl(r[j], j);
        float inv = rsqrtf(d);
        if (l == j) r[j] = d * inv;
        else if (l > j) r[j] *= inv;
        if (l == 0) dinv[b0 + j] = inv;
#pragma unroll
        for (int t = j + 1; t < 16; ++t) {
          float Ltj = __shfl(r[j], t);
          if (l >= t) r[t] -= r[j] * Ltj;
        }
      }
#pragma unroll
      for (int t = 0; t < 16; ++t) if (t <= l) sh[(b0 + l) * DSTR + b0 + t] = r[t];
      // corner inverse: lane l = column l of V
      float x[16];
#pragma unroll
      for (int i = 0; i < 16; ++i) {
        float s = (l == i) ? 1.0f : 0.0f;
#pragma unroll
        for (int t = 0; t < 16; ++t)
          if (t < i) s -= __shfl(r[t], i) * x[t];
        x[i] = s * dinv[b0 + i];
      }
#pragma unroll
      for (int i = 0; i < 16; ++i)
        if (i > l) sh[(b0 + l) * DSTR + b0 + i] = x[i];  // V^T strict upper
    }
    __syncthreads();
    const int base = b0 + 16, nbl = NB - base;
    if (nbl > 0) {
      // strip TRSM: L[r][b0+c] = sum_{t<=c} A[r][b0+t] * V[c][t]
      const int cnt = nbl * 16;
      float pv[7];
#pragma unroll
      for (int e = 0; e < 7; ++e) {
        int idx = tid + e * 256;
        if (idx < cnt) {
          int r2 = base + (idx >> 4), c2 = idx & 15;
          float s = 0.0f;
          for (int t = 0; t < c2; ++t)
            s += sh[r2 * DSTR + b0 + t] * sh[(b0 + t) * DSTR + b0 + c2];  // V^T[t][c2]
          s += sh[r2 * DSTR + b0 + c2] * dinv[b0 + c2];
          pv[e] = s;
        }
      }
      __syncthreads();
#pragma unroll
      for (int e = 0; e < 7; ++e) {
        int idx = tid + e * 256;
        if (idx < cnt) {
          int r2 = base + (idx >> 4), c2 = idx & 15;
          sh[r2 * DSTR + b0 + c2] = pv[e];
        }
      }
      __syncthreads();
      // rank-16 trailing update (lower incl diag)
      for (int i = tid >> 3; i < nbl; i += 32) {
        const float* ai = &sh[(base + i) * DSTR + b0];
        float4 a0 = *(const float4*)ai,       a1 = *(const float4*)(ai + 4);
        float4 a2 = *(const float4*)(ai + 8), a3 = *(const float4*)(ai + 12);
        for (int j = tid & 7; j <= i; j += 8) {
          const float* bj = &sh[(base + j) * DSTR + b0];
          float4 c0 = *(const float4*)bj,       c1 = *(const float4*)(bj + 4);
          float4 c2 = *(const float4*)(bj + 8), c3 = *(const float4*)(bj + 12);
          float s = a0.x*c0.x + a0.y*c0.y + a0.z*c0.z + a0.w*c0.w
                  + a1.x*c1.x + a1.y*c1.y + a1.z*c1.z + a1.w*c1.w
                  + a2.x*c2.x + a2.y*c2.y + a2.z*c2.z + a2.w*c2.w
                  + a3.x*c3.x + a3.y*c3.y + a3.z*c3.z + a3.w*c3.w;
          sh[(base + i) * DSTR + base + j] -= s;
        }
      }
      __syncthreads();
    }
  }
  // convert corner 7
  if (tid < 16) {
    int l = tid;
    const int a0 = 112;
    float colv[16];
#pragma unroll
    for (int i = 0; i < 16; ++i) colv[i] = sh[(a0 + l) * DSTR + a0 + i];
#pragma unroll
    for (int i = 0; i < 16; ++i) {
      float v = (i > l) ? colv[i] : ((i == l) ? dinv[a0 + l] : 0.0f);
      sh[(a0 + i) * DSTR + a0 + l] = v;
    }
  }
  __syncthreads();

  // ---- recursive doubling: 3 levels x 2 GEMM phases, in place ----
  asm_levelA<16>(sh, tid); __syncthreads();
  asm_levelB<16>(sh, tid); __syncthreads();
  asm_levelA<32>(sh, tid); __syncthreads();
  asm_levelB<32>(sh, tid); __syncthreads();
  asm_levelA<64>(sh, tid); __syncthreads();
  asm_levelB<64>(sh, tid); __syncthreads();

  // ---- write U (predicated: upper 16-blocks = 0) ----
#pragma unroll
  for (int e = 0; e < 16; ++e) {
    int idx = tid + (e << 8);
    int i = idx >> 5, f4 = idx & 31;
    float4 v;
    if ((i >> 4) >= (f4 >> 2)) v = *(const float4*)&sh[i * DSTR + 4 * f4];
    else v = make_float4(0.f, 0.f, 0.f, 0.f);
    *(float4*)(U + (size_t)i * NB + 4 * f4) = v;
  }
}

// ---------------- panel TRSM as GEMM: P := P_old * U^T ----------------
__global__ __launch_bounds__(256, 2) void k_trsm(float* __restrict__ M,
                                                 const float* __restrict__ Ug, int k0) {
  __shared__ float Pa[NB * PSTR];
  __shared__ float Pb[NB * PSTR];
  int tid = threadIdx.x;
  int g4 = tid >> 4, rr = g4 * 8, cm = tid & 15;
  int r0 = k0 + NB + blockIdx.x * NB;
  float acc[8][8] = {};
  for (int ch = 0; ch < 2; ++ch) {
    int kc = k0 + ch * 64;
    __syncthreads();
#pragma unroll
    for (int i = 0; i < 8; ++i) {
      int idx = tid + (i << 8);
      int r = idx >> 4, f4 = idx & 15;
      *(float4*)&Pa[r * PSTR + 4 * f4] = *(const float4*)(M + (size_t)(r0 + r) * N + kc + 4 * f4);
      *(float4*)&Pb[r * PSTR + 4 * f4] = *(const float4*)(Ug + (size_t)r * NB + ch * 64 + 4 * f4);
    }
    __syncthreads();
#pragma unroll 2
    for (int tc = 0; tc < 64; tc += 4) {
      float4 a4[8], b4[8];
#pragma unroll
      for (int q = 0; q < 8; ++q) a4[q] = *(const float4*)&Pa[(rr + ((q + g4) & 7)) * PSTR + tc];
#pragma unroll
      for (int w = 0; w < 8; ++w) b4[w] = *(const float4*)&Pb[(cm + 16 * w) * PSTR + tc];
#pragma unroll
      for (int q = 0; q < 8; ++q)
#pragma unroll
        for (int w = 0; w < 8; ++w)
          acc[q][w] += a4[q].x * b4[w].x + a4[q].y * b4[w].y
                     + a4[q].z * b4[w].z + a4[q].w * b4[w].w;
    }
  }
  for (int q = 0; q < 8; ++q) {
    int row = r0 + rr + ((q + g4) & 7);
    float* mp = M + (size_t)row * N + k0 + cm;
#pragma unroll
    for (int w = 0; w < 8; ++w) mp[16 * w] = acc[q][w];
  }
}

// ---------------- fused forward solve step k ----------------
__global__ __launch_bounds__(256) void k_fsolve(float* __restrict__ S,
                                                float* __restrict__ X,
                                                const float* __restrict__ M,
                                                const float* __restrict__ Uk,
                                                int k0) {
  __shared__ float Xl[NB][BSTR];
  __shared__ float Aa[16][TSTR];
  __shared__ float Bb[16][BSTR];
  int tid = threadIdx.x;
  int id = xcd_map(blockIdx.x, gridDim.x);
  int d = id >> 3;
  int b0 = (id & 7) * 64;
  int i0g = k0 + d * NB;
  int ii = (tid >> 3) * 4, bl = (tid & 7) * 8;
  float acc[4][8] = {};
  for (int tch = 0; tch < NB; tch += 16) {
#pragma unroll
    for (int it = 0; it < 2; ++it) {
      int idx = tid + it * 256;
      int j = idx >> 2, f4 = idx & 3;
      const float4 v = *(const float4*)(Uk + (size_t)j * NB + tch + 4 * f4);
      Aa[4 * f4 + 0][j] = v.x; Aa[4 * f4 + 1][j] = v.y;
      Aa[4 * f4 + 2][j] = v.z; Aa[4 * f4 + 3][j] = v.w;
    }
    {
      int t = tid >> 4, f = tid & 15;
      *(float4*)&Bb[t][4 * f] = *(const float4*)(S + (size_t)(k0 + tch + t) * NRHS + b0 + 4 * f);
    }
    __syncthreads();
#pragma unroll 4
    for (int t = 0; t < 16; ++t) {
      float4 a0 = *(const float4*)&Aa[t][ii];
      float4 b0v = *(const float4*)&Bb[t][bl];
      float4 b1v = *(const float4*)&Bb[t][bl + 4];
      float av[4] = {a0.x, a0.y, a0.z, a0.w};
      float bv[8] = {b0v.x, b0v.y, b0v.z, b0v.w, b1v.x, b1v.y, b1v.z, b1v.w};
#pragma unroll
      for (int q = 0; q < 4; ++q)
#pragma unroll
        for (int w = 0; w < 8; ++w) acc[q][w] += av[q] * bv[w];
    }
    __syncthreads();
  }
  if (d == 0) {
    for (int q = 0; q < 4; ++q) {
      float* xp = X + (size_t)(k0 + ii + q) * NRHS + b0 + bl;
      float4 x0 = {acc[q][0], acc[q][1], acc[q][2], acc[q][3]};
      float4 x1 = {acc[q][4], acc[q][5], acc[q][6], acc[q][7]};
      *(float4*)xp = x0; *((float4*)xp + 1) = x1;
    }
    return;
  }
  for (int q = 0; q < 4; ++q) {
    float4 x0 = {acc[q][0], acc[q][1], acc[q][2], acc[q][3]};
    float4 x1 = {acc[q][4], acc[q][5], acc[q][6], acc[q][7]};
    *(float4*)&Xl[ii + q][bl] = x0; *(float4*)&Xl[ii + q][bl + 4] = x1;
  }
  __syncthreads();
  float acc2[4][8] = {};
  for (int tch = 0; tch < NB; tch += 16) {
    for (int idx = tid; idx < 512; idx += 256) {
      int r = idx >> 2, q = idx & 3;
      const float4 v = *(const float4*)(M + (size_t)(i0g + r) * N + k0 + tch + 4 * q);
      Aa[4 * q + 0][r] = v.x; Aa[4 * q + 1][r] = v.y;
      Aa[4 * q + 2][r] = v.z; Aa[4 * q + 3][r] = v.w;
    }
    __syncthreads();
#pragma unroll 4
    for (int t = 0; t < 16; ++t) {
      float4 a0 = *(const float4*)&Aa[t][ii];
      float4 b0v = *(const float4*)&Xl[tch + t][bl];
      float4 b1v = *(const float4*)&Xl[tch + t][bl + 4];
      float av[4] = {a0.x, a0.y, a0.z, a0.w};
      float bv[8] = {b0v.x, b0v.y, b0v.z, b0v.w, b1v.x, b1v.y, b1v.z, b1v.w};
#pragma unroll
      for (int q = 0; q < 4; ++q)
#pragma unroll
        for (int w = 0; w < 8; ++w) acc2[q][w] += av[q] * bv[w];
    }
    __syncthreads();
  }
  for (int q = 0; q < 4; ++q) {
    float* sp = S + (size_t)(i0g + ii + q) * NRHS + b0 + bl;
    float4 x0 = *(float4*)sp, x1 = *((float4*)sp + 1);
    x0.x -= acc2[q][0]; x0.y -= acc2[q][1]; x0.z -= acc2[q][2]; x0.w -= acc2[q][3];
    x1.x -= acc2[q][4]; x1.y -= acc2[q][5]; x1.z -= acc2[q][6]; x1.w -= acc2[q][7];
    *(float4*)sp = x0; *((float4*)sp + 1) = x1;
  }
}

// ---------------- fused backward solve step k (descending) ----------------
__global__ __launch_bounds__(256) void k_bsolve(float* __restrict__ X,
                                                float* __restrict__ S,
                                                const float* __restrict__ M,
                                                const float* __restrict__ Uk,
                                                int k0) {
  __shared__ float Xl[NB][BSTR];
  __shared__ float Aa[16][TSTR];
  __shared__ float Bb[16][BSTR];
  int tid = threadIdx.x;
  int id = xcd_map(blockIdx.x, gridDim.x);
  int d = id >> 3;
  int b0 = (id & 7) * 64;
  int i0g = k0 - d * NB;
  int ii = (tid >> 3) * 4, bl = (tid & 7) * 8;
  float acc[4][8] = {};
  for (int tch = 0; tch < NB; tch += 16) {
    for (int idx = tid; idx < 512; idx += 256) {
      int t = idx >> 5, f = idx & 31;
      *(float4*)&Aa[t][4 * f] = *(const float4*)(Uk + (size_t)(tch + t) * NB + 4 * f);
    }
    {
      int t = tid >> 4, f = tid & 15;
      *(float4*)&Bb[t][4 * f] = *(const float4*)(X + (size_t)(k0 + tch + t) * NRHS + b0 + 4 * f);
    }
    __syncthreads();
#pragma unroll 4
    for (int t = 0; t < 16; ++t) {
      float4 a0 = *(const float4*)&Aa[t][ii];
      float4 b0v = *(const float4*)&Bb[t][bl];
      float4 b1v = *(const float4*)&Bb[t][bl + 4];
      float av[4] = {a0.x, a0.y, a0.z, a0.w};
      float bv[8] = {b0v.x, b0v.y, b0v.z, b0v.w, b1v.x, b1v.y, b1v.z, b1v.w};
#pragma unroll
      for (int q = 0; q < 4; ++q)
#pragma unroll
        for (int w = 0; w < 8; ++w) acc[q][w] += av[q] * bv[w];
    }
    __syncthreads();
  }
  if (d == 0) {
    for (int q = 0; q < 4; ++q) {
      float* sp = S + (size_t)(k0 + ii + q) * NRHS + b0 + bl;
      float4 x0 = {acc[q][0], acc[q][1], acc[q][2], acc[q][3]};
      float4 x1 = {acc[q][4], acc[q][5], acc[q][6], acc[q][7]};
      *(float4*)sp = x0; *((float4*)sp + 1) = x1;
    }
    return;
  }
  for (int q = 0; q < 4; ++q) {
    float4 x0 = {acc[q][0], acc[q][1], acc[q][2], acc[q][3]};
    float4 x1 = {acc[q][4], acc[q][5], acc[q][6], acc[q][7]};
    *(float4*)&Xl[ii + q][bl] = x0; *(float4*)&Xl[ii + q][bl + 4] = x1;
  }
  __syncthreads();
  float acc2[4][8] = {};
  for (int tch = 0; tch < NB; tch += 16) {
    for (int idx = tid; idx < 512; idx += 256) {
      int t = idx >> 5, f = idx & 31;
      *(float4*)&Aa[t][4 * f] = *(const float4*)(M + (size_t)(k0 + tch + t) * N + i0g + 4 * f);
    }
    __syncthreads();
#pragma unroll 4
    for (int t = 0; t < 16; ++t) {
      float4 a0 = *(const float4*)&Aa[t][ii];
      float4 b0v = *(const float4*)&Xl[tch + t][bl];
      float4 b1v = *(const float4*)&Xl[tch + t][bl + 4];
      float av[4] = {a0.x, a0.y, a0.z, a0.w};
      float bv[8] = {b0v.x, b0v.y, b0v.z, b0v.w, b1v.x, b1v.y, b1v.z, b1v.w};
#pragma unroll
      for (int q = 0; q < 4; ++q)
#pragma unroll
        for (int w = 0; w < 8; ++w) acc2[q][w] += av[q] * bv[w];
    }
    __syncthreads();
  }
  for (int q = 0; q < 4; ++q) {
    float* xp = X + (size_t)(i0g + ii + q) * NRHS + b0 + bl;
    float4 x0 = *(float4*)xp, x1 = *((float4*)xp + 1);
    x0.x -= acc2[q][0]; x0.y -= acc2[q][1]; x0.z -= acc2[q][2]; x0.w -= acc2[q][3];
    x1.x -= acc2[q][4]; x1.y -= acc2[q][5]; x1.z -= acc2[q][6]; x1.w -= acc2[q][7];
    *(float4*)xp = x0; *((float4*)xp + 1) = x1;
  }
}

// ---------------- denom + normalize + transpose to output ----------------
__global__ __launch_bounds__(256) void k_final(const float* __restrict__ S,
                                               const float* __restrict__ K,
                                               const float* __restrict__ a_ptr,
                                               float* __restrict__ out) {
  __shared__ float red[256];
  int b = blockIdx.x, tid = threadIdx.x;
  float s = 0.0f;
  for (int i = tid; i < N; i += 256) s += S[(size_t)i * NRHS + b] * K[(size_t)b * N + i];
  red[tid] = s; __syncthreads();
  for (int w = 128; w > 0; w >>= 1) { if (tid < w) red[tid] += red[tid + w]; __syncthreads(); }
  float inv = 1.0f / (a_ptr[0] * red[0]);
  for (int i = tid; i < N; i += 256) out[(size_t)b * N + i] = S[(size_t)i * NRHS + b] * inv;
}

extern "C" void kernel_launch(void* const* d_in, const int* in_sizes, int n_in,
                              void* d_out, int out_size, void* d_ws, size_t ws_size,
                              hipStream_t stream) {
  const float* Kb    = (const float*)d_in[0];
  const float* a     = (const float*)d_in[1];
  const float* exc   = (const float*)d_in[2];
  const float* imp   = (const float*)d_in[3];
  const float* Phi   = (const float*)d_in[4];
  const float* gamma = (const float*)d_in[5];
  float* out = (float*)d_out;

  float* M  = (float*)d_ws;                        // n*n            (64 MiB)
  float* S  = M + (size_t)N * N;                   // n*NRHS         (8 MiB)
  float* X  = S + (size_t)N * NRHS;                // n*NRHS         (8 MiB)
  float* U  = X + (size_t)N * NRHS;                // 32 * 128*128   (2 MiB)
  float* c  = U + (size_t)32 * NB * NB;            // scalars

  k_scalars<<<1, 256, 0, stream>>>(imp, exc, gamma, c);
  k_build_M<<<N * N / 1024, 256, 0, stream>>>(Phi, c, M);
  k_transpose<<<dim3(N / 32, NRHS / 32), 256, 0, stream>>>(Kb, S);

  // potrf(0) standalone
  k_syrk_potrf<<<1, 256, 0, stream>>>(M, U, 0, -1);
  for (int k = 0; k <= 30; ++k) {
    int k0 = k * NB;
    k_trsm<<<31 - k, 256, 0, stream>>>(M, U + (size_t)k * NB * NB, k0);
    int T = 31 - k;
    int pairs = (T * (T + 1)) / 2;   // logical block 0 = lookahead potrf(k+1)
    k_syrk_potrf<<<pairs, 256, 0, stream>>>(M, U + (size_t)(k + 1) * NB * NB, k + 1, k0);
  }
  for (int k = 0; k < 32; ++k)
    k_fsolve<<<8 * (32 - k), 256, 0, stream>>>(S, X, M, U + (size_t)k * NB * NB, k * NB);
  for (int k = 31; k >= 0; --k)
    k_bsolve<<<8 * (k + 1), 256, 0, stream>>>(X, S, M, U + (size_t)k * NB * NB, k * NB);
  k_final<<<NRHS, 256, 0, stream>>>(S, Kb, a, out);
}